// Round 7
// baseline (685.155 us; speedup 1.0000x reference)
//
#include <hip/hip_runtime.h>
#include <hip/hip_bf16.h>
#include <stdint.h>

// B=8192, D=2048, M=8, C=1000; padded: CPAD=1024, NPAD=8192 (n' = c*8 + m)
#define BDIM 8192
#define DDIM 2048
#define MDIM 8
#define CDIM 1000
#define CPAD 1024
#define NPAD 8192

typedef __attribute__((ext_vector_type(8))) short bf16x8;
typedef __attribute__((ext_vector_type(4))) float f32x4;
typedef __attribute__((ext_vector_type(16))) float f32x16;

__device__ __forceinline__ unsigned short f2bf(float f) {
    union { float f; unsigned u; } v; v.f = f;
    unsigned r = v.u + 0x7fffu + ((v.u >> 16) & 1u);   // RNE
    return (unsigned short)(r >> 16);
}

__device__ __forceinline__ void gl_lds16(const void* g, void* l) {
    __builtin_amdgcn_global_load_lds(
        (const __attribute__((address_space(1))) void*)g,
        (__attribute__((address_space(3))) void*)l,
        16, 0, 0);
}

// ---------------- prep: cast x (fp32 -> bf16) ----------------
__global__ void cast_x_kernel(const float4* __restrict__ x, ushort* __restrict__ xb) {
    int i = blockIdx.x * blockDim.x + threadIdx.x;
    float4 v = x[i];
    ushort4 o;
    o.x = f2bf(v.x); o.y = f2bf(v.y); o.z = f2bf(v.z); o.w = f2bf(v.w);
    *(ushort4*)&xb[(size_t)i * 4] = o;
}

// ---- prep: model_weights (M,D,C) -> wb[n'=c*8+m][d], zero-pad c>=1000 ----
__global__ void prep_w(const float* __restrict__ MW, ushort* __restrict__ wb) {
    __shared__ float tile[32][33];
    int m  = blockIdx.z;
    int c0 = blockIdx.x * 32;
    int d0 = blockIdx.y * 32;
    int tx = threadIdx.x, ty = threadIdx.y;
    const float* src = MW + (size_t)m * DDIM * CDIM;
#pragma unroll
    for (int i = 0; i < 4; i++) {
        int d = d0 + ty + i * 8;
        int c = c0 + tx;
        tile[ty + i * 8][tx] = (c < CDIM) ? src[(size_t)d * CDIM + c] : 0.f;
    }
    __syncthreads();
#pragma unroll
    for (int i = 0; i < 4; i++) {
        int c = c0 + ty + i * 8;
        int d = d0 + tx;
        wb[(size_t)(c * 8 + m) * DDIM + d] = f2bf(tile[tx][ty + i * 8]);
    }
}

// ---- prep: resnet_weight (D, 8000) -> rb[n'=c*8+m][d], zero-pad c>=1000 ----
__global__ void prep_r(const float* __restrict__ R, ushort* __restrict__ rb) {
    __shared__ float tile[32][33];
    int m  = blockIdx.z;
    int c0 = blockIdx.x * 32;
    int d0 = blockIdx.y * 32;
    int tx = threadIdx.x, ty = threadIdx.y;
#pragma unroll
    for (int i = 0; i < 4; i++) {
        int d = d0 + ty + i * 8;
        int c = c0 + tx;
        tile[ty + i * 8][tx] = (c < CDIM) ? R[(size_t)d * (MDIM * CDIM) + m * CDIM + c] : 0.f;
    }
    __syncthreads();
#pragma unroll
    for (int i = 0; i < 4; i++) {
        int c = c0 + ty + i * 8;
        int d = d0 + tx;
        rb[(size_t)(c * 8 + m) * DDIM + d] = f2bf(tile[tx][ty + i * 8]);
    }
}

// ---- prep: biases -> interleaved padded float arrays [NPAD] ----
__global__ void prep_bias(const float* __restrict__ mb, const float* __restrict__ rbv,
                          float* __restrict__ mb2, float* __restrict__ rb2) {
    int n = blockIdx.x * 256 + threadIdx.x;   // 0..8191
    int c = n >> 3, m = n & 7;
    mb2[n] = (c < CDIM) ? mb[m * CDIM + c] : 0.f;
    rb2[n] = (c < CDIM) ? rbv[m * CDIM + c] : 0.f;
}

// ------------- fused dual-B GEMM, 4-phase, 32x32x16 MFMA -------------
#define BM 256
#define BN 128
#define BK 64
#define NT (DDIM / BK)   // 32

// stage one 16KB unit (128 rows x 64 ushorts), inverse-swizzled global source,
// linear LDS dest (wave-uniform base + lane*16). 2 gl_lds insts per thread.
#define STAGE(G, L) do {                                                       \
    _Pragma("unroll")                                                          \
    for (int it_ = 0; it_ < 2; ++it_) {                                        \
        int ci_ = it_ * 512 + tid;                                             \
        int r_ = ci_ >> 3, cc_ = ci_ & 7;                                      \
        gl_lds16((G) + (size_t)r_ * DDIM + (size_t)((cc_ ^ (r_ & 7)) << 3),    \
                 (L) + (size_t)(it_ * 512 + wbase) * 8);                       \
    }                                                                          \
} while (0)

// A frags for row-half H (contiguous 128-row staged unit), kh pair {KH0,KH0+1}.
// 32x32x16 A layout: row = lane&31, k-chunk = (lane>>5)*8, frag rows i2*32.
#define LDA32(AC, H, KH0) do {                                                 \
    _Pragma("unroll")                                                          \
    for (int i2_ = 0; i2_ < 2; i2_++)                                          \
    _Pragma("unroll")                                                          \
    for (int q_ = 0; q_ < 2; q_++) {                                           \
        int row_ = (H) * 128 + wm * 64 + i2_ * 32 + (lane & 31);               \
        int cc_ = ((KH0) + q_) * 2 + (lane >> 5);                              \
        af[i2_][q_] = *(const bf16x8*)&(AC)[row_ * BK + ((cc_ ^ (row_ & 7)) << 3)]; \
    }                                                                          \
} while (0)

#define LDB32(BS, BF, KH0) do {                                                \
    _Pragma("unroll")                                                          \
    for (int q_ = 0; q_ < 2; q_++) {                                           \
        int row_ = wn * 32 + (lane & 31);                                      \
        int cc_ = ((KH0) + q_) * 2 + (lane >> 5);                              \
        BF[q_] = *(const bf16x8*)&(BS)[row_ * BK + ((cc_ ^ (row_ & 7)) << 3)]; \
    }                                                                          \
} while (0)

// 8 MFMA (both accs, 2 row-frags, kh pair); acc dep distance = 4 insts
#define MM32(H) do {                                                           \
    __builtin_amdgcn_s_setprio(1);                                             \
    _Pragma("unroll")                                                          \
    for (int q_ = 0; q_ < 2; q_++) {                                           \
        acc1[(H)*2+0] = __builtin_amdgcn_mfma_f32_32x32x16_bf16(af[0][q_], bf1[q_], acc1[(H)*2+0], 0, 0, 0); \
        acc1[(H)*2+1] = __builtin_amdgcn_mfma_f32_32x32x16_bf16(af[1][q_], bf1[q_], acc1[(H)*2+1], 0, 0, 0); \
        acc2[(H)*2+0] = __builtin_amdgcn_mfma_f32_32x32x16_bf16(af[0][q_], bf2[q_], acc2[(H)*2+0], 0, 0, 0); \
        acc2[(H)*2+1] = __builtin_amdgcn_mfma_f32_32x32x16_bf16(af[1][q_], bf2[q_], acc2[(H)*2+1], 0, 0, 0); \
    }                                                                          \
    __builtin_amdgcn_s_setprio(0);                                             \
} while (0)

#define FENCE() asm volatile("" ::: "memory")
#define BARRIER() do { FENCE(); __builtin_amdgcn_s_barrier(); FENCE(); } while (0)
#define WAITV(N) asm volatile("s_waitcnt vmcnt(" #N ")" ::: "memory")

__global__ __launch_bounds__(512, 2) void gemm_fused(
    const ushort* __restrict__ xb, const ushort* __restrict__ wb,
    const ushort* __restrict__ rb,
    const float* __restrict__ mb2, const float* __restrict__ rb2,
    float* __restrict__ out) {
    __shared__ ushort As[2][BM * BK];    // 2 x 32 KB
    __shared__ ushort B1s[2][BN * BK];   // 2 x 16 KB
    __shared__ ushort B2s[2][BN * BK];   // 2 x 16 KB

    int tid   = threadIdx.x;
    int lane  = tid & 63;
    int wid   = tid >> 6;        // 0..7
    int wm    = wid >> 2;        // 0..1 -> 64-row half within each A unit
    int wn    = wid & 3;         // 0..3 -> 32-col quarter
    int wbase = tid & ~63;

    // T1: bijective XCD swizzle (2048 % 8 == 0)
    int wg = blockIdx.x;
    int wgs = (wg & 7) * 256 + (wg >> 3);
    int tile_m = wgs >> 6;       // 0..31
    int tile_n = wgs & 63;       // 0..63
    int brow = tile_m * BM;
    int bn0  = tile_n * BN;

    const ushort* xg  = xb + (size_t)brow * DDIM;
    const ushort* w1g = wb + (size_t)bn0 * DDIM;
    const ushort* w2g = rb + (size_t)bn0 * DDIM;

    f32x16 acc1[4] = {};   // per-wave 128x32 output, 4 row-frags of 32
    f32x16 acc2[4] = {};
    bf16x8 af[2][2], bf1[2], bf2[2];

    // Units: U0 = A rows 0..127, U1 = B1, U2 = B2, U3 = A rows 128..255.
    // Invariant at K-tile top: outstanding = [U3(t)] (2 insts); rest drained.
    STAGE(xg,               As[0]);              // U0(0)
    STAGE(w1g,              B1s[0]);             // U1(0)
    STAGE(w2g,              B2s[0]);             // U2(0)
    STAGE(xg + 128 * DDIM,  As[0] + 128 * BK);   // U3(0)
    WAITV(2);                 // drains U0,U1,U2(0); leaves [U3(0)]
    BARRIER();

    // Per K-tile: P1{h0,kh01|stage U0'}, P2{h0,kh23|U1'|drain U3},
    //             P3{h1,kh01|U2'}, P4{h1,kh23|U3'|drain U0'..U2'}.
    // Tail iteration stages in-bounds garbage (never consumed).
#pragma unroll 2
    for (int t = 0; t < NT; ++t) {
        int buf = t & 1;
        ushort* Ac  = As[buf];
        ushort* B1c = B1s[buf];
        ushort* B2c = B2s[buf];
        ushort* An  = As[buf ^ 1];
        ushort* B1n = B1s[buf ^ 1];
        ushort* B2n = B2s[buf ^ 1];
        const int kn = (t + 1) * BK;

        // P1: 8 reads (A-h0 kh01, B1/B2 kh01) | stage U0(t+1) | 8 MFMA
        LDA32(Ac, 0, 0);
        LDB32(B1c, bf1, 0);
        LDB32(B2c, bf2, 0);
        STAGE(xg + kn, An);
        BARRIER();
        MM32(0);
        BARRIER();

        // P2: 8 reads (A-h0 kh23, B1/B2 kh23) | stage U1(t+1) | 8 MFMA
        LDA32(Ac, 0, 2);
        LDB32(B1c, bf1, 2);
        LDB32(B2c, bf2, 2);
        STAGE(w1g + kn, B1n);
        BARRIER();
        MM32(0);
        WAITV(4);            // drains U3(t) [P3 reads it]; 2-phase slack
        BARRIER();

        // P3: 8 reads (A-h1 kh01, B1/B2 kh01) | stage U2(t+1) | 8 MFMA
        LDA32(Ac, 1, 0);
        LDB32(B1c, bf1, 0);
        LDB32(B2c, bf2, 0);
        STAGE(w2g + kn, B2n);
        BARRIER();
        MM32(1);
        BARRIER();

        // P4: 8 reads (A-h1 kh23, B1/B2 kh23) | stage U3(t+1) | 8 MFMA
        LDA32(Ac, 1, 2);
        LDB32(B1c, bf1, 2);
        LDB32(B2c, bf2, 2);
        STAGE(xg + 128 * DDIM + kn, An + 128 * BK);
        BARRIER();
        MM32(1);
        WAITV(2);            // drains U0,U1,U2(t+1) [next P1 reads them]
        BARRIER();
    }
    WAITV(0);  // garbage-stage DMA must not outlive this workgroup's LDS

    // ---- epilogue: p = (acc1+b1)(acc2+b2); reduce over m (8 adjacent n');
    // 32x32 C/D: col = lane&31, row = (r&3) + 8*(r>>2) + 4*(lane>>5).
    // frag fi -> rows (fi>>1)*128 + wm*64 + (fi&1)*32. 3x shfl_xor over m. ----
    {
        int np = bn0 + wn * 32 + (lane & 31);
        float bb1 = mb2[np];
        float bb2 = rb2[np];
        int c = tile_n * 16 + wn * 4 + ((lane & 31) >> 3);
#pragma unroll
        for (int fi = 0; fi < 4; fi++) {
#pragma unroll
            for (int r = 0; r < 16; r++) {
                float p = (acc1[fi][r] + bb1) * (acc2[fi][r] + bb2);
                p += __shfl_xor(p, 1);
                p += __shfl_xor(p, 2);
                p += __shfl_xor(p, 4);
                if ((lane & 7) == 0 && c < CDIM) {
                    int row = brow + (fi >> 1) * 128 + wm * 64 + (fi & 1) * 32
                              + (r & 3) + 8 * (r >> 2) + 4 * (lane >> 5);
                    out[(size_t)row * CDIM + c] = p;
                }
            }
        }
    }
}

extern "C" void kernel_launch(void* const* d_in, const int* in_sizes, int n_in,
                              void* d_out, int out_size, void* d_ws, size_t ws_size,
                              hipStream_t stream) {
    const float* x   = (const float*)d_in[0];   // [8192][2048]
    const float* mw  = (const float*)d_in[1];   // [8][2048][1000]
    const float* mb  = (const float*)d_in[2];   // [8][1000]
    const float* rw  = (const float*)d_in[3];   // [2048][8000]
    const float* rbv = (const float*)d_in[4];   // [8000]
    float* out = (float*)d_out;                 // [8192][1000]

    char* ws = (char*)d_ws;
    ushort* xb  = (ushort*)ws;                                  // 33,554,432 B
    ushort* wb  = (ushort*)(ws + (size_t)33554432);             // 33,554,432 B
    ushort* rb  = (ushort*)(ws + (size_t)67108864);             // 33,554,432 B
    float*  mb2 = (float*)(ws + (size_t)100663296);             // 32,768 B
    float*  rb2 = (float*)(ws + (size_t)100696064);             // 32,768 B

    cast_x_kernel<<<BDIM * DDIM / (256 * 4), 256, 0, stream>>>((const float4*)x, xb);
    prep_w<<<dim3(CPAD / 32, DDIM / 32, MDIM), dim3(32, 8), 0, stream>>>(mw, wb);
    prep_r<<<dim3(CPAD / 32, DDIM / 32, MDIM), dim3(32, 8), 0, stream>>>(rw, rb);
    prep_bias<<<NPAD / 256, 256, 0, stream>>>(mb, rbv, mb2, rb2);

    gemm_fused<<<dim3((BDIM / BM) * (NPAD / BN)), 512, 0, stream>>>(xb, wb, rb, mb2, rb2, out);
}